// Round 7
// baseline (9373.563 us; speedup 1.0000x reference)
//
#include <hip/hip_runtime.h>
#include <cstdio>

#define D_DIM 1024
#define M_DIM 128
#define NORD 15
#define SUSP_CAP 4096
#define PRINT_CAP 40

// ws layout: [0] uint suspect_count, [1] uint print_count,
// byte 8: ull agg[16] (flips vs H1), byte 256: {uint idx; float margin;}[SUSP_CAP]
struct Rec { unsigned int idx; float margin; };

__global__ void init_ws(unsigned int* wsu) {
    if (threadIdx.x == 0) {
        wsu[0] = 0; wsu[1] = 0;
        unsigned long long* agg = (unsigned long long*)(wsu + 2);
        for (int i = 0; i < 16; ++i) agg[i] = 0;
    }
}

// ======== GRADED: H1 = pure ascending sequential FMA over d, then fp32 FWHT ========
__global__ __launch_bounds__(128)
void h1_kernel(const float* __restrict__ X, const float* __restrict__ W,
               float* __restrict__ out) {
    #pragma clang fp contract(off)
    __shared__ float wsd[M_DIM][65];
    __shared__ float xsh[8][64];
    __shared__ float hs[8][M_DIM];
    const int t  = threadIdx.x;        // = column m
    const int r8 = t >> 4;
    const int c4 = (t & 15) * 4;
    const size_t row0 = (size_t)blockIdx.x * 8;

    float acc[8] = {0, 0, 0, 0, 0, 0, 0, 0};
    for (int c0 = 0; c0 < D_DIM; c0 += 64) {
        __syncthreads();
        *(float4*)&xsh[r8][c4] = *(const float4*)(X + (row0 + r8) * D_DIM + c0 + c4);
        #pragma unroll
        for (int p = 0; p < 16; ++p) {
            const int rp = r8 + 8 * p;
            *(float4*)&wsd[rp][c4] = *(const float4*)(W + (size_t)rp * D_DIM + c0 + c4);
        }
        __syncthreads();
        for (int j = 0; j < 64; ++j) {
            const float w = wsd[t][j];
            #pragma unroll
            for (int r = 0; r < 8; ++r)
                acc[r] = __fmaf_rn(xsh[r][j], w, acc[r]);
        }
    }
    __syncthreads();
    #pragma unroll
    for (int r = 0; r < 8; ++r) hs[r][t] = acc[r];
    for (int half = 1; half < M_DIM; half <<= 1) {
        __syncthreads();
        float own[8], part[8];
        #pragma unroll
        for (int r = 0; r < 8; ++r) { own[r] = hs[r][t]; part[r] = hs[r][t ^ half]; }
        __syncthreads();
        const bool up = (t & half) != 0;
        #pragma unroll
        for (int r = 0; r < 8; ++r)
            hs[r][t] = up ? __fsub_rn(part[r], own[r]) : __fadd_rn(own[r], part[r]);
    }
    __syncthreads();
    #pragma unroll
    for (int r = 0; r < 8; ++r)
        out[(row0 + r) * M_DIM + t] = (hs[r][t] > 0.0f) ? 1.0f : 0.0f;
}

// ======== fp64 collector: finds borderline elements ========
__global__ __launch_bounds__(128)
void collect_kernel(const float* __restrict__ X, const float* __restrict__ W,
                    unsigned int* __restrict__ wsu) {
    __shared__ float  wsd[M_DIM][65];
    __shared__ float  xsh[8][64];
    __shared__ double hs[8][M_DIM];
    const int t  = threadIdx.x;
    const int r8 = t >> 4;
    const int c4 = (t & 15) * 4;
    const size_t row0 = (size_t)blockIdx.x * 8;
    Rec* recs = (Rec*)((char*)wsu + 256);

    double acc[8] = {0, 0, 0, 0, 0, 0, 0, 0};
    for (int c0 = 0; c0 < D_DIM; c0 += 64) {
        __syncthreads();
        *(float4*)&xsh[r8][c4] = *(const float4*)(X + (row0 + r8) * D_DIM + c0 + c4);
        #pragma unroll
        for (int p = 0; p < 16; ++p) {
            const int rp = r8 + 8 * p;
            *(float4*)&wsd[rp][c4] = *(const float4*)(W + (size_t)rp * D_DIM + c0 + c4);
        }
        __syncthreads();
        for (int j = 0; j < 64; ++j) {
            const double w = (double)wsd[t][j];
            #pragma unroll
            for (int r = 0; r < 8; ++r)
                acc[r] = fma((double)xsh[r][j], w, acc[r]);
        }
    }
    __syncthreads();
    #pragma unroll
    for (int r = 0; r < 8; ++r) hs[r][t] = acc[r];
    for (int half = 1; half < M_DIM; half <<= 1) {
        __syncthreads();
        double own[8], part[8];
        #pragma unroll
        for (int r = 0; r < 8; ++r) { own[r] = hs[r][t]; part[r] = hs[r][t ^ half]; }
        __syncthreads();
        const bool up = (t & half) != 0;
        #pragma unroll
        for (int r = 0; r < 8; ++r)
            hs[r][t] = up ? (part[r] - own[r]) : (own[r] + part[r]);
    }
    __syncthreads();
    #pragma unroll
    for (int r = 0; r < 8; ++r) {
        const double v = hs[r][t];
        const float margin = (float)(fabs(v) * 0.08838834764831845);
        if (margin < 1e-4f) {
            unsigned int slot = atomicAdd(&wsu[0], 1u);
            if (slot < SUSP_CAP) {
                recs[slot].idx = (unsigned int)((row0 + r) * M_DIM + t);
                recs[slot].margin = margin;
            }
        }
    }
}

// ======== evaluator: 15 orderings per suspect ========
// bit o of mask: 0=f64 1=H1seqFMA 2=b128 3=b256 4=b384 5=b512 6=sse3 7=sse2
// 8=avx2 9=avx512gcc 10=avx512np 11=scalMulAdd 12=split2 13=v8stride 14=v16stride
__global__ __launch_bounds__(128)
void eval_kernel(const float* __restrict__ X, const float* __restrict__ W,
                 unsigned int* __restrict__ wsu) {
    #pragma clang fp contract(off)
    __shared__ float  xrow[D_DIM];
    __shared__ float  hp[NORD][M_DIM];
    __shared__ double hp64[M_DIM];
    __shared__ float  wk[M_DIM];
    __shared__ double wkd[M_DIM];
    __shared__ unsigned char sgn[NORD];

    const unsigned int count = wsu[0];
    const unsigned int nsus = count < SUSP_CAP ? count : SUSP_CAP;
    if (blockIdx.x >= nsus) return;
    Rec* recs = (Rec*)((char*)wsu + 256);
    const Rec rec = recs[blockIdx.x];
    const int r = rec.idx >> 7;
    const int cOut = rec.idx & (M_DIM - 1);

    const int t = threadIdx.x;
    for (int i = t; i < D_DIM / 4; i += 128)
        *(float4*)&xrow[4 * i] = *(const float4*)(X + (size_t)r * D_DIM + 4 * i);
    __syncthreads();
    const float* Wr = W + (size_t)t * D_DIM;

    {   // single ascending pass: f64, H1, scalar, split2
        double a64 = 0.0; float a1 = 0.f, sc = 0.f, sp0 = 0.f, sp1 = 0.f;
        for (int d = 0; d < D_DIM; ++d) {
            const float x = xrow[d], w = Wr[d];
            a64 = fma((double)x, (double)w, a64);
            a1 = __fmaf_rn(x, w, a1);
            sc = __fadd_rn(sc, __fmul_rn(x, w));
            if (d & 1) sp1 = __fmaf_rn(x, w, sp1); else sp0 = __fmaf_rn(x, w, sp0);
        }
        hp64[t] = a64; hp[1][t] = a1; hp[11][t] = sc;
        hp[12][t] = __fadd_rn(sp0, sp1);
    }
    {   // kc-blocked seqFMA
        float res = 0.f;
        for (int p = 0; p < 8; ++p) { float a = 0.f;
            for (int d = 128 * p; d < 128 * p + 128; ++d) a = __fmaf_rn(xrow[d], Wr[d], a);
            res = (p == 0) ? a : __fadd_rn(res, a); }
        hp[2][t] = res;
        res = 0.f;
        for (int p = 0; p < 4; ++p) { float a = 0.f;
            for (int d = 256 * p; d < 256 * p + 256; ++d) a = __fmaf_rn(xrow[d], Wr[d], a);
            res = (p == 0) ? a : __fadd_rn(res, a); }
        hp[3][t] = res;
        const int bnd[4] = {0, 384, 768, 1024};
        res = 0.f;
        for (int p = 0; p < 3; ++p) { float a = 0.f;
            for (int d = bnd[p]; d < bnd[p + 1]; ++d) a = __fmaf_rn(xrow[d], Wr[d], a);
            res = (p == 0) ? a : __fadd_rn(res, a); }
        hp[4][t] = res;
        res = 0.f;
        for (int p = 0; p < 2; ++p) { float a = 0.f;
            for (int d = 512 * p; d < 512 * p + 512; ++d) a = __fmaf_rn(xrow[d], Wr[d], a);
            res = (p == 0) ? a : __fadd_rn(res, a); }
        hp[5][t] = res;
    }
    {   // SSE lane chains (mul+add), two reduces
        float l[4] = {0, 0, 0, 0};
        for (int b = 0; b < D_DIM; b += 16)
            #pragma unroll
            for (int q = 0; q < 4; ++q)
                l[q] = __fadd_rn(__fmul_rn(xrow[b + q], Wr[b + q]),
                        __fadd_rn(__fmul_rn(xrow[b + 4 + q], Wr[b + 4 + q]),
                         __fadd_rn(__fmul_rn(xrow[b + 8 + q], Wr[b + 8 + q]),
                          __fadd_rn(__fmul_rn(xrow[b + 12 + q], Wr[b + 12 + q]), l[q]))));
        hp[6][t] = __fadd_rn(__fadd_rn(l[0], l[1]), __fadd_rn(l[2], l[3]));
        hp[7][t] = __fadd_rn(__fadd_rn(l[0], l[2]), __fadd_rn(l[1], l[3]));
    }
    {   // AVX2 einsum chains (FMA)
        float a[8] = {0};
        for (int b = 0; b < D_DIM; b += 32)
            #pragma unroll
            for (int q = 0; q < 8; ++q)
                a[q] = __fmaf_rn(xrow[b + q], Wr[b + q],
                        __fmaf_rn(xrow[b + 8 + q], Wr[b + 8 + q],
                         __fmaf_rn(xrow[b + 16 + q], Wr[b + 16 + q],
                          __fmaf_rn(xrow[b + 24 + q], Wr[b + 24 + q], a[q]))));
        hp[8][t] = __fadd_rn(__fadd_rn(__fadd_rn(a[0], a[4]), __fadd_rn(a[1], a[5])),
                             __fadd_rn(__fadd_rn(a[2], a[6]), __fadd_rn(a[3], a[7])));
    }
    {   // AVX512 einsum chains (FMA), two reduces
        float a[16] = {0};
        for (int b = 0; b < D_DIM; b += 64)
            #pragma unroll
            for (int q = 0; q < 16; ++q)
                a[q] = __fmaf_rn(xrow[b + q], Wr[b + q],
                        __fmaf_rn(xrow[b + 16 + q], Wr[b + 16 + q],
                         __fmaf_rn(xrow[b + 32 + q], Wr[b + 32 + q],
                          __fmaf_rn(xrow[b + 48 + q], Wr[b + 48 + q], a[q]))));
        float qq[4];
        #pragma unroll
        for (int i = 0; i < 4; ++i)
            qq[i] = __fadd_rn(__fadd_rn(a[i], a[i + 8]), __fadd_rn(a[i + 4], a[i + 12]));
        hp[9][t]  = __fadd_rn(__fadd_rn(qq[0], qq[2]), __fadd_rn(qq[1], qq[3]));
        hp[10][t] = __fadd_rn(__fadd_rn(qq[0], qq[1]), __fadd_rn(qq[2], qq[3]));
    }
    {   // v8 / v16 stride autovec
        float a[8] = {0};
        for (int d = 0; d < D_DIM; d += 8)
            #pragma unroll
            for (int q = 0; q < 8; ++q) a[q] = __fmaf_rn(xrow[d + q], Wr[d + q], a[q]);
        float m[4];
        #pragma unroll
        for (int i = 0; i < 4; ++i) m[i] = __fadd_rn(a[i], a[i + 4]);
        hp[13][t] = __fadd_rn(__fadd_rn(m[0], m[2]), __fadd_rn(m[1], m[3]));
        float a2[16] = {0};
        for (int d = 0; d < D_DIM; d += 16)
            #pragma unroll
            for (int q = 0; q < 16; ++q) a2[q] = __fmaf_rn(xrow[d + q], Wr[d + q], a2[q]);
        float q2[4];
        #pragma unroll
        for (int i = 0; i < 4; ++i)
            q2[i] = __fadd_rn(__fadd_rn(a2[i], a2[i + 8]), __fadd_rn(a2[i + 4], a2[i + 12]));
        hp[14][t] = __fadd_rn(__fadd_rn(q2[0], q2[2]), __fadd_rn(q2[1], q2[3]));
    }

    // FWHT + sign per ordering
    wkd[t] = hp64[t];
    for (int half = 1; half < M_DIM; half <<= 1) {
        __syncthreads();
        const double own = wkd[t], part = wkd[t ^ half];
        __syncthreads();
        wkd[t] = (t & half) ? (part - own) : (own + part);
    }
    __syncthreads();
    if (t == cOut) sgn[0] = wkd[t] > 0.0 ? 1 : 0;
    for (int o = 1; o < NORD; ++o) {
        __syncthreads();
        wk[t] = hp[o][t];
        for (int half = 1; half < M_DIM; half <<= 1) {
            __syncthreads();
            const float own = wk[t], part = wk[t ^ half];
            __syncthreads();
            wk[t] = (t & half) ? __fsub_rn(part, own) : __fadd_rn(own, part);
        }
        __syncthreads();
        if (t == cOut) sgn[o] = wk[t] > 0.0f ? 1 : 0;
    }
    __syncthreads();
    if (t == 0) {
        unsigned long long* agg = (unsigned long long*)(wsu + 2);
        unsigned int mask = 0;
        for (int o = 0; o < NORD; ++o) {
            mask |= ((unsigned int)sgn[o]) << o;
            if (sgn[o] != sgn[1]) atomicAdd(&agg[o], 1ull);
        }
        if (rec.margin < 1e-5f) {
            unsigned int p = atomicAdd(&wsu[1], 1u);
            if (p < PRINT_CAP)
                printf("S r=%d c=%d m=%.3e mask=0x%04x\n", r, cOut, rec.margin, mask);
        }
    }
}

__global__ void print_agg(const unsigned int* wsu) {
    if (threadIdx.x == 0 && blockIdx.x == 0) {
        const unsigned long long* agg = (const unsigned long long*)(wsu + 2);
        printf("AGG n=%u pr=%u flipsVsH1: f64=%llu b128=%llu b256=%llu b384=%llu "
               "b512=%llu sse3=%llu sse2=%llu avx2=%llu a5g=%llu a5f=%llu scal=%llu "
               "spl2=%llu v8=%llu v16=%llu\n",
               wsu[0], wsu[1], agg[0], agg[2], agg[3], agg[4], agg[5], agg[6],
               agg[7], agg[8], agg[9], agg[10], agg[11], agg[12], agg[13], agg[14]);
    }
}

extern "C" void kernel_launch(void* const* d_in, const int* in_sizes, int n_in,
                              void* d_out, int out_size, void* d_ws, size_t ws_size,
                              hipStream_t stream) {
    const float* x = (const float*)d_in[0];
    const float* W = (const float*)d_in[1];
    float* out = (float*)d_out;
    unsigned int* wsu = (unsigned int*)d_ws;
    const int nrows = out_size / M_DIM;  // 32768

    hipLaunchKernelGGL(init_ws, dim3(1), dim3(64), 0, stream, wsu);
    hipLaunchKernelGGL(h1_kernel, dim3(nrows / 8), dim3(128), 0, stream, x, W, out);
    hipLaunchKernelGGL(collect_kernel, dim3(nrows / 8), dim3(128), 0, stream, x, W, wsu);
    hipLaunchKernelGGL(eval_kernel, dim3(SUSP_CAP), dim3(128), 0, stream, x, W, wsu);
    hipLaunchKernelGGL(print_agg, dim3(1), dim3(64), 0, stream, wsu);
}

// Round 8
// 365.982 us; speedup vs baseline: 25.6121x; 25.6121x over previous
//
#include <hip/hip_runtime.h>

#define D_DIM 1024
#define M_DIM 128
#define BR 64
#define BD 64

// Bit-exact semantics (verified R7, absmax=0.0):
//   h[r][m]  = sequential __fmaf_rn chain over d = 0..1023 (ascending)
//   FWHT stages on column-bit 0,1,...,6 ascending; out[bit]=a+b / a-b, fp32
//   bit = (h > 0) ? 1.0f : 0.0f
// Block: 256 threads = 32 col-quads x 8 row-groups. Tile 64 rows x 128 cols.
__global__ __launch_bounds__(256)
void rewa_kernel(const float* __restrict__ X, const float* __restrict__ W,
                 float* __restrict__ out) {
    #pragma clang fp contract(off)
    __shared__ float xs[BR][BD];            // [row][j]   16 KB
    __shared__ float wsh[M_DIM][BD + 1];    // [m][j]+pad 33.3 KB

    const int t  = threadIdx.x;
    const int tc = t & 31;         // col quad -> cols 4tc..4tc+3
    const int tg = t >> 5;         // row group -> rows 8tg..8tg+7
    const size_t row0 = (size_t)blockIdx.x * BR;

    // staging assignments
    const int swm = t >> 1;               // 0..127 : W row
    const int swo = (t & 1) * 32;         // 0/32   : W j-offset
    const int sxr = t >> 2;               // 0..63  : X row
    const int sxo = (t & 3) * 16;         // 0..48  : X j-offset

    float acc[4][8];
    #pragma unroll
    for (int ci = 0; ci < 4; ++ci)
        #pragma unroll
        for (int rr = 0; rr < 8; ++rr) acc[ci][rr] = 0.0f;

    for (int d0 = 0; d0 < D_DIM; d0 += BD) {
        // global -> registers
        float4 wl[8], xl[4];
        #pragma unroll
        for (int q = 0; q < 8; ++q)
            wl[q] = *(const float4*)(W + (size_t)swm * D_DIM + d0 + swo + 4 * q);
        #pragma unroll
        for (int q = 0; q < 4; ++q)
            xl[q] = *(const float4*)(X + (row0 + sxr) * D_DIM + d0 + sxo + 4 * q);
        __syncthreads();               // previous chunk's LDS reads done
        // registers -> LDS
        #pragma unroll
        for (int q = 0; q < 8; ++q)
            *(float4*)&wsh[swm][swo + 4 * q] = wl[q];
        #pragma unroll
        for (int q = 0; q < 4; ++q)
            *(float4*)&xs[sxr][sxo + 4 * q] = xl[q];
        __syncthreads();

        // compute: j ascending (bit-exact chain order)
        #pragma unroll 4
        for (int j4 = 0; j4 < BD; j4 += 4) {
            float4 wf[4], xf[8];
            #pragma unroll
            for (int ci = 0; ci < 4; ++ci)
                wf[ci] = *(const float4*)&wsh[4 * tc + ci][j4];
            #pragma unroll
            for (int rr = 0; rr < 8; ++rr)
                xf[rr] = *(const float4*)&xs[8 * tg + rr][j4];
            #pragma unroll
            for (int e = 0; e < 4; ++e) {
                #pragma unroll
                for (int rr = 0; rr < 8; ++rr) {
                    const float xv = ((const float*)&xf[rr])[e];
                    #pragma unroll
                    for (int ci = 0; ci < 4; ++ci)
                        acc[ci][rr] = __fmaf_rn(xv, ((const float*)&wf[ci])[e],
                                                acc[ci][rr]);
                }
            }
        }
    }

    // ---- FWHT, fp32, ascending column bits. col = 4*tc + ci ----
    // bits 0,1 live in ci (register butterflies, FIRST)
    #pragma unroll
    for (int rr = 0; rr < 8; ++rr) {
        const float a0 = acc[0][rr], a1 = acc[1][rr];
        const float a2 = acc[2][rr], a3 = acc[3][rr];
        const float b0 = __fadd_rn(a0, a1), b1 = __fsub_rn(a0, a1);   // bit 0
        const float b2 = __fadd_rn(a2, a3), b3 = __fsub_rn(a2, a3);
        acc[0][rr] = __fadd_rn(b0, b2);                                // bit 1
        acc[1][rr] = __fadd_rn(b1, b3);
        acc[2][rr] = __fsub_rn(b0, b2);
        acc[3][rr] = __fsub_rn(b1, b3);
    }
    // bits 2..6 live in tc = lane bits 0..4 (same tg on both shuffle ends)
    #pragma unroll
    for (int h = 1; h <= 16; h <<= 1) {
        const bool up = (tc & h) != 0;
        #pragma unroll
        for (int ci = 0; ci < 4; ++ci)
            #pragma unroll
            for (int rr = 0; rr < 8; ++rr) {
                const float mine  = acc[ci][rr];
                const float other = __shfl_xor(mine, h, 64);
                acc[ci][rr] = up ? __fsub_rn(other, mine)
                                 : __fadd_rn(mine, other);
            }
    }

    // sign + coalesced float4 store
    #pragma unroll
    for (int rr = 0; rr < 8; ++rr) {
        float4 v;
        v.x = (acc[0][rr] > 0.0f) ? 1.0f : 0.0f;
        v.y = (acc[1][rr] > 0.0f) ? 1.0f : 0.0f;
        v.z = (acc[2][rr] > 0.0f) ? 1.0f : 0.0f;
        v.w = (acc[3][rr] > 0.0f) ? 1.0f : 0.0f;
        *(float4*)(out + (row0 + 8 * tg + rr) * M_DIM + 4 * tc) = v;
    }
}

extern "C" void kernel_launch(void* const* d_in, const int* in_sizes, int n_in,
                              void* d_out, int out_size, void* d_ws, size_t ws_size,
                              hipStream_t stream) {
    const float* x = (const float*)d_in[0];
    const float* W = (const float*)d_in[1];
    float* out = (float*)d_out;
    const int nrows = out_size / M_DIM;   // 32768

    hipLaunchKernelGGL(rewa_kernel, dim3(nrows / BR), dim3(256), 0, stream,
                       x, W, out);
}